// Round 1
// 870.654 us; speedup vs baseline: 1.2436x; 1.2436x over previous
//
#include <hip/hip_runtime.h>
#include <math.h>

#define B_  64
#define Cc  128
#define L_  3136

typedef __bf16 b8v __attribute__((ext_vector_type(8)));
typedef float  f4v __attribute__((ext_vector_type(4)));

__device__ __forceinline__ f4v mfma16(b8v a, b8v b, f4v c) {
    return __builtin_amdgcn_mfma_f32_16x16x32_bf16(a, b, c, 0, 0, 0);
}
__device__ __forceinline__ int region(int h, int w) {
    int a = (h < 49) ? 0 : ((h < 53) ? 1 : 2);
    int b = (w < 49) ? 0 : ((w < 53) ? 1 : 2);
    return a * 3 + b;
}

// ws layout: bf16 weights [0,196608) elems; biasmask f32[4][4][64][64] at byte 393216
__global__ __launch_bounds__(256) void prep_kernel(
    const float* __restrict__ qkv_w, const float* __restrict__ proj_w,
    const float* __restrict__ fc1_w, const float* __restrict__ fc2_w,
    const float* __restrict__ rpb,
    __bf16* __restrict__ wsb, float* __restrict__ bm)
{
    int i = blockIdx.x * 256 + threadIdx.x;
    if      (i <  49152) wsb[i] = (__bf16)qkv_w[i];
    else if (i <  65536) wsb[i] = (__bf16)proj_w[i - 49152];
    else if (i < 131072) wsb[i] = (__bf16)fc1_w[i - 65536];
    else if (i < 196608) wsb[i] = (__bf16)fc2_w[i - 131072];
    else {
        int idx = i - 196608;  // ((wt*4+h)*64+ii)*64+jj
        int jj = idx & 63, ii = (idx >> 6) & 63, h = (idx >> 12) & 3, wt = idx >> 14;
        float v;
        if (jj >= 49)      v = -1e30f;
        else if (ii >= 49) v = 0.f;
        else {
            int ih = ii / 7, iw = ii - ih * 7, jh = jj / 7, jw = jj - jh * 7;
            v = rpb[((ih - jh + 6) * 13 + (iw - jw + 6)) * 4 + h];
            int WH = (wt & 2) ? 49 : 0, WW = (wt & 1) ? 49 : 0;
            if (region(WH + ih, WW + iw) != region(WH + jh, WW + jw)) v -= 100.f;
        }
        bm[idx] = v;
    }
}

// ---- kernel A: LN1 + SW-MSA + proj + residual ----
// one block per (batch, window); LDS 40448 -> 4 blocks/CU
__global__ __launch_bounds__(256, 4) void swin_kernel(
    const float* __restrict__ x,
    const float* __restrict__ g1, const float* __restrict__ b1,
    const float* __restrict__ qkv_b, const float* __restrict__ proj_b,
    const __bf16* __restrict__ wqkv, const __bf16* __restrict__ wproj,
    const float* __restrict__ bm,
    float* __restrict__ out)
{
    __shared__ __bf16 a_s[64 * 136];               // LN1 out
    __shared__ __align__(16) char u_s[23040];      // phase union
    __bf16* QKs = (__bf16*)u_s;                    // 64 x 72 (Q | K)
    __bf16* VTs = (__bf16*)(u_s + 9216);           // 32 x 72 (V^T)
    __bf16* PSs = (__bf16*)(u_s + 13824);          // 64 x 72 (softmax P)
    __bf16* OSs = (__bf16*)u_s;                    // 64 x 136 (attn O)

    const int tid = threadIdx.x, w = tid >> 6, lane = tid & 63;
    const int quad = lane >> 4, r16 = lane & 15;
    const int blk = blockIdx.x, b = blk >> 6, wi = blk & 63;
    const int wh = wi >> 3, ww = wi & 7;
    const int wt = ((wh == 7) ? 2 : 0) | ((ww == 7) ? 1 : 0);
    const float scale = 0.17677669529663687f;  // 1/sqrt(32)

    // ---- LN1 with shifted gather (2 tokens/iter, 4 interleaved shfl chains) ----
    for (int t = w; t < 49; t += 8) {
        int t2 = t + 4; bool has2 = (t2 < 49);
        int th = t / 7, tw = t - th * 7;
        int sh = wh * 7 + th + 3; if (sh >= 56) sh -= 56;
        int sw = ww * 7 + tw + 3; if (sw >= 56) sw -= 56;
        int rowA = (b * L_ + sh * 56 + sw) * Cc;
        int rowB = rowA;
        if (has2) {
            int th2 = t2 / 7, tw2 = t2 - th2 * 7;
            int sh2 = wh * 7 + th2 + 3; if (sh2 >= 56) sh2 -= 56;
            int sw2 = ww * 7 + tw2 + 3; if (sw2 >= 56) sw2 -= 56;
            rowB = (b * L_ + sh2 * 56 + sw2) * Cc;
        }
        float a0 = x[rowA + lane], a1 = x[rowA + 64 + lane];
        float c0 = x[rowB + lane], c1 = x[rowB + 64 + lane];
        float sA = a0 + a1, qA = a0 * a0 + a1 * a1;
        float sB = c0 + c1, qB = c0 * c0 + c1 * c1;
        for (int off = 32; off; off >>= 1) {
            sA += __shfl_down(sA, off, 64); qA += __shfl_down(qA, off, 64);
            sB += __shfl_down(sB, off, 64); qB += __shfl_down(qB, off, 64);
        }
        sA = __shfl(sA, 0, 64); qA = __shfl(qA, 0, 64);
        sB = __shfl(sB, 0, 64); qB = __shfl(qB, 0, 64);
        {
            float mu = sA * (1.f / 128.f);
            float rs = rsqrtf(qA * (1.f / 128.f) - mu * mu + 1e-5f);
            a_s[t * 136 + lane]      = (__bf16)((a0 - mu) * rs * g1[lane]      + b1[lane]);
            a_s[t * 136 + 64 + lane] = (__bf16)((a1 - mu) * rs * g1[64 + lane] + b1[64 + lane]);
        }
        if (has2) {
            float mu = sB * (1.f / 128.f);
            float rs = rsqrtf(qB * (1.f / 128.f) - mu * mu + 1e-5f);
            a_s[t2 * 136 + lane]      = (__bf16)((c0 - mu) * rs * g1[lane]      + b1[lane]);
            a_s[t2 * 136 + 64 + lane] = (__bf16)((c1 - mu) * rs * g1[64 + lane] + b1[64 + lane]);
        }
    }
    for (int idx = tid; idx < 15 * 128; idx += 256) {
        int rr = idx >> 7, cc = idx & 127;
        a_s[(49 + rr) * 136 + cc] = (__bf16)0.f;
    }
    __syncthreads();

    // ---- attention: O accumulates in registers ----
    f4v o_acc[4][2];
    #pragma unroll
    for (int h = 0; h < 4; h++)
        #pragma unroll
        for (int n = 0; n < 2; n++)
            o_acc[h][n] = (f4v){0.f, 0.f, 0.f, 0.f};

    const float* bmw = bm + wt * 4 * 4096;

    for (int h = 0; h < 4; h++) {
        // QKV for this head: wave w owns M-strip mt=w; nt=0..5 (Q,Q,K,K,V,V)
        {
            const __bf16* ap = &a_s[(w * 16 + r16) * 136 + quad * 8];
            b8v A0 = *(const b8v*)(ap);
            b8v A1 = *(const b8v*)(ap + 32);
            b8v A2 = *(const b8v*)(ap + 64);
            b8v A3 = *(const b8v*)(ap + 96);
            #pragma unroll
            for (int nt = 0; nt < 6; nt++) {
                int base = (nt < 2) ? (h * 32 + nt * 16)
                         : (nt < 4) ? (128 + h * 32 + (nt - 2) * 16)
                                    : (256 + h * 32 + (nt - 4) * 16);
                const __bf16* bp = wqkv + (base + r16) * 128 + quad * 8;
                f4v acc = {0.f, 0.f, 0.f, 0.f};
                acc = mfma16(A0, *(const b8v*)(bp),      acc);
                acc = mfma16(A1, *(const b8v*)(bp + 32), acc);
                acc = mfma16(A2, *(const b8v*)(bp + 64), acc);
                acc = mfma16(A3, *(const b8v*)(bp + 96), acc);
                float bias = qkv_b[base + r16];
                #pragma unroll
                for (int r = 0; r < 4; r++) {
                    int m = w * 16 + quad * 4 + r;
                    float v = acc[r] + bias;
                    if (nt < 2)      QKs[m * 72 + nt * 16 + r16]            = (__bf16)(v * scale);
                    else if (nt < 4) QKs[m * 72 + 32 + (nt - 2) * 16 + r16] = (__bf16)v;
                    else             VTs[((nt - 4) * 16 + r16) * 72 + m]    = (__bf16)v;
                }
            }
        }
        __syncthreads();

        // S = Q K^T + (bias+mask table)
        f4v s[4];
        {
            b8v qf = *(const b8v*)&QKs[(w * 16 + r16) * 72 + quad * 8];
            #pragma unroll
            for (int nt = 0; nt < 4; nt++) {
                b8v kf = *(const b8v*)&QKs[(nt * 16 + r16) * 72 + 32 + quad * 8];
                f4v z = {0.f, 0.f, 0.f, 0.f};
                s[nt] = mfma16(qf, kf, z);
            }
            const float* bmp = bmw + h * 4096 + (w * 16 + quad * 4) * 64 + r16;
            #pragma unroll
            for (int nt = 0; nt < 4; nt++)
                #pragma unroll
                for (int r = 0; r < 4; r++)
                    s[nt][r] += bmp[r * 64 + nt * 16];
        }
        // softmax: 4 rows, shfl chains interleaved
        {
            float mx[4], sm[4];
            #pragma unroll
            for (int r = 0; r < 4; r++)
                mx[r] = fmaxf(fmaxf(s[0][r], s[1][r]), fmaxf(s[2][r], s[3][r]));
            #pragma unroll
            for (int mk = 1; mk < 16; mk <<= 1)
                #pragma unroll
                for (int r = 0; r < 4; r++)
                    mx[r] = fmaxf(mx[r], __shfl_xor(mx[r], mk, 64));
            #pragma unroll
            for (int r = 0; r < 4; r++) {
                s[0][r] = expf(s[0][r] - mx[r]);
                s[1][r] = expf(s[1][r] - mx[r]);
                s[2][r] = expf(s[2][r] - mx[r]);
                s[3][r] = expf(s[3][r] - mx[r]);
                sm[r] = s[0][r] + s[1][r] + s[2][r] + s[3][r];
            }
            #pragma unroll
            for (int mk = 1; mk < 16; mk <<= 1)
                #pragma unroll
                for (int r = 0; r < 4; r++)
                    sm[r] += __shfl_xor(sm[r], mk, 64);
            #pragma unroll
            for (int r = 0; r < 4; r++) {
                float inv = 1.f / sm[r];
                s[0][r] *= inv; s[1][r] *= inv; s[2][r] *= inv; s[3][r] *= inv;
            }
        }
        // P -> LDS (D->A transform, wave-local strip)
        #pragma unroll
        for (int nt = 0; nt < 4; nt++)
            #pragma unroll
            for (int r = 0; r < 4; r++)
                PSs[(w * 16 + quad * 4 + r) * 72 + nt * 16 + r16] = (__bf16)s[nt][r];

        // O += P V (register accumulation)
        #pragma unroll
        for (int nt = 0; nt < 2; nt++)
            #pragma unroll
            for (int ks = 0; ks < 2; ks++) {
                b8v pf = *(const b8v*)&PSs[(w * 16 + r16) * 72 + ks * 32 + quad * 8];
                b8v vf = *(const b8v*)&VTs[(nt * 16 + r16) * 72 + ks * 32 + quad * 8];
                o_acc[h][nt] = mfma16(pf, vf, o_acc[h][nt]);
            }
        __syncthreads();
    }

    // O regs -> LDS (union now free)
    #pragma unroll
    for (int h = 0; h < 4; h++)
        #pragma unroll
        for (int nt = 0; nt < 2; nt++)
            #pragma unroll
            for (int r = 0; r < 4; r++)
                OSs[(w * 16 + quad * 4 + r) * 136 + h * 32 + nt * 16 + r16] = (__bf16)o_acc[h][nt][r];
    __syncthreads();

    // ---- proj + residual: write x1 to out (fp32); LN2/MLP moved to kernel B ----
    {
        const __bf16* ap = &OSs[(w * 16 + r16) * 136 + quad * 8];
        b8v A0 = *(const b8v*)(ap);
        b8v A1 = *(const b8v*)(ap + 32);
        b8v A2 = *(const b8v*)(ap + 64);
        b8v A3 = *(const b8v*)(ap + 96);
        #pragma unroll
        for (int nt = 0; nt < 8; nt++) {
            const __bf16* bp = wproj + (nt * 16 + r16) * 128 + quad * 8;
            f4v acc = {0.f, 0.f, 0.f, 0.f};
            acc = mfma16(A0, *(const b8v*)(bp),      acc);
            acc = mfma16(A1, *(const b8v*)(bp + 32), acc);
            acc = mfma16(A2, *(const b8v*)(bp + 64), acc);
            acc = mfma16(A3, *(const b8v*)(bp + 96), acc);
            int col = nt * 16 + r16;
            float pb = proj_b[col];
            #pragma unroll
            for (int r = 0; r < 4; r++) {
                int t = w * 16 + quad * 4 + r;
                if (t < 49) {
                    int th = t / 7, tw = t - th * 7;
                    int sh = wh * 7 + th + 3; if (sh >= 56) sh -= 56;
                    int sw = ww * 7 + tw + 3; if (sw >= 56) sw -= 56;
                    int off = (b * L_ + sh * 56 + sw) * Cc + col;
                    out[off] = x[off] + acc[r] + pb;
                }
            }
        }
    }
}

// ---- kernel B: LN2 + fc1 + GELU + fc2 + residual; token-parallel, barrier-free ----
// 256 threads = 4 waves, each wave owns 16 tokens end-to-end with a private
// 16x520 bf16 h1 buffer (wave-local LDS => no __syncthreads anywhere).
// LDS 66560 -> 2 blocks/CU.
__global__ __launch_bounds__(256, 2) void mlp_kernel(
    float* __restrict__ out,
    const float* __restrict__ g2, const float* __restrict__ b2,
    const __bf16* __restrict__ wfc1, const __bf16* __restrict__ wfc2,
    const float* __restrict__ fc1_b, const float* __restrict__ fc2_b)
{
    __shared__ __bf16 h1_s[4][16 * 520];
    const int tid = threadIdx.x, w = tid >> 6, lane = tid & 63;
    const int quad = lane >> 4, r16 = lane & 15;
    __bf16* h1 = h1_s[w];
    const int rowbase = blockIdx.x * 64 + w * 16;

    // ---- LN2: lane handles token row (lane>>2), channels (lane&3)*32..+31 ----
    {
        const int r = lane >> 2, sub = lane & 3;
        const float* xp = out + (rowbase + r) * Cc + sub * 32;
        f4v xa[8];
        #pragma unroll
        for (int j = 0; j < 8; j++) xa[j] = *(const f4v*)(xp + j * 4);
        float s = 0.f, q = 0.f;
        #pragma unroll
        for (int j = 0; j < 8; j++)
            #pragma unroll
            for (int e = 0; e < 4; e++) { float v = xa[j][e]; s += v; q += v * v; }
        s += __shfl_xor(s, 1, 64); q += __shfl_xor(q, 1, 64);
        s += __shfl_xor(s, 2, 64); q += __shfl_xor(q, 2, 64);
        float mu = s * (1.f / 128.f);
        float rs = rsqrtf(q * (1.f / 128.f) - mu * mu + 1e-5f);
        #pragma unroll
        for (int j = 0; j < 8; j += 2) {
            int c = sub * 32 + j * 4;
            f4v gg0 = *(const f4v*)(g2 + c), gg1 = *(const f4v*)(g2 + c + 4);
            f4v bb0 = *(const f4v*)(b2 + c), bb1 = *(const f4v*)(b2 + c + 4);
            b8v o;
            #pragma unroll
            for (int e = 0; e < 4; e++) {
                o[e]     = (__bf16)((xa[j][e]     - mu) * rs * gg0[e] + bb0[e]);
                o[4 + e] = (__bf16)((xa[j + 1][e] - mu) * rs * gg1[e] + bb1[e]);
            }
            *(b8v*)(h1 + r * 520 + c) = o;
        }
    }
    // wave-local LDS round-trip: in-order DS per wave, no barrier needed.

    // A-fragments for fc1 (rows r16, k = quad*8 + i*32): hoist to registers,
    // then the LN region (cols 0..127) is free to be overwritten by h1.
    b8v af[4];
    #pragma unroll
    for (int i = 0; i < 4; i++)
        af[i] = *(const b8v*)(h1 + r16 * 520 + quad * 8 + i * 32);

    // ---- fc1 + exact GELU -> h1 (16 x 512) ----
    #pragma unroll 4
    for (int nt = 0; nt < 32; nt++) {
        const __bf16* bp = wfc1 + (nt * 16 + r16) * 128 + quad * 8;
        f4v acc = {0.f, 0.f, 0.f, 0.f};
        acc = mfma16(af[0], *(const b8v*)(bp),      acc);
        acc = mfma16(af[1], *(const b8v*)(bp + 32), acc);
        acc = mfma16(af[2], *(const b8v*)(bp + 64), acc);
        acc = mfma16(af[3], *(const b8v*)(bp + 96), acc);
        float bias = fc1_b[nt * 16 + r16];
        #pragma unroll
        for (int rr = 0; rr < 4; rr++) {
            float v = acc[rr] + bias;
            v = 0.5f * v * (1.f + erff(v * 0.70710678118654752f));
            h1[(quad * 4 + rr) * 520 + nt * 16 + r16] = (__bf16)v;
        }
    }

    // ---- fc2 + residual RMW ----
    b8v hf[16];
    #pragma unroll
    for (int ks = 0; ks < 16; ks++)
        hf[ks] = *(const b8v*)(h1 + r16 * 520 + quad * 8 + ks * 32);

    #pragma unroll 2
    for (int nt = 0; nt < 8; nt++) {
        const __bf16* bp = wfc2 + (nt * 16 + r16) * 512 + quad * 8;
        f4v acc = {0.f, 0.f, 0.f, 0.f};
        #pragma unroll
        for (int ks = 0; ks < 16; ks++)
            acc = mfma16(hf[ks], *(const b8v*)(bp + ks * 32), acc);
        float bias = fc2_b[nt * 16 + r16];
        #pragma unroll
        for (int rr = 0; rr < 4; rr++) {
            int row = rowbase + quad * 4 + rr;
            out[row * Cc + nt * 16 + r16] += acc[rr] + bias;
        }
    }
}

extern "C" void kernel_launch(void* const* d_in, const int* in_sizes, int n_in,
                              void* d_out, int out_size, void* d_ws, size_t ws_size,
                              hipStream_t stream) {
    // 0 x, 1 ln1_g, 2 ln1_b, 3 qkv_w, 4 qkv_b, 5 rpb_table, 6 proj_w, 7 proj_b,
    // 8 ln2_g, 9 ln2_b, 10 fc1_w, 11 fc1_b, 12 fc2_w, 13 fc2_b
    __bf16* wsb = (__bf16*)d_ws;
    float*  bmp = (float*)((char*)d_ws + 393216);
    prep_kernel<<<1024, 256, 0, stream>>>(
        (const float*)d_in[3], (const float*)d_in[6],
        (const float*)d_in[10], (const float*)d_in[12],
        (const float*)d_in[5], wsb, bmp);
    swin_kernel<<<B_ * 64, 256, 0, stream>>>(
        (const float*)d_in[0],
        (const float*)d_in[1], (const float*)d_in[2],
        (const float*)d_in[4], (const float*)d_in[7],
        wsb, wsb + 49152,
        bmp, (float*)d_out);
    mlp_kernel<<<B_ * 49, 256, 0, stream>>>(
        (float*)d_out,
        (const float*)d_in[8], (const float*)d_in[9],
        wsb + 65536, wsb + 131072,
        (const float*)d_in[11], (const float*)d_in[13]);
}

// Round 2
// 676.173 us; speedup vs baseline: 1.6013x; 1.2876x over previous
//
#include <hip/hip_runtime.h>
#include <math.h>

#define B_  64
#define Cc  128
#define L_  3136

typedef __bf16 b8v __attribute__((ext_vector_type(8)));
typedef float  f4v __attribute__((ext_vector_type(4)));

__device__ __forceinline__ f4v mfma16(b8v a, b8v b, f4v c) {
    return __builtin_amdgcn_mfma_f32_16x16x32_bf16(a, b, c, 0, 0, 0);
}
__device__ __forceinline__ int region(int h, int w) {
    int a = (h < 49) ? 0 : ((h < 53) ? 1 : 2);
    int b = (w < 49) ? 0 : ((w < 53) ? 1 : 2);
    return a * 3 + b;
}

// ws layout: bf16 weights [0,196608) elems; biasmask f32[4][4][64][64] at byte 393216
__global__ __launch_bounds__(256) void prep_kernel(
    const float* __restrict__ qkv_w, const float* __restrict__ proj_w,
    const float* __restrict__ fc1_w, const float* __restrict__ fc2_w,
    const float* __restrict__ rpb,
    __bf16* __restrict__ wsb, float* __restrict__ bm)
{
    int i = blockIdx.x * 256 + threadIdx.x;
    if      (i <  49152) wsb[i] = (__bf16)qkv_w[i];
    else if (i <  65536) wsb[i] = (__bf16)proj_w[i - 49152];
    else if (i < 131072) wsb[i] = (__bf16)fc1_w[i - 65536];
    else if (i < 196608) wsb[i] = (__bf16)fc2_w[i - 131072];
    else {
        int idx = i - 196608;  // ((wt*4+h)*64+ii)*64+jj
        int jj = idx & 63, ii = (idx >> 6) & 63, h = (idx >> 12) & 3, wt = idx >> 14;
        float v;
        if (jj >= 49)      v = -1e30f;
        else if (ii >= 49) v = 0.f;
        else {
            int ih = ii / 7, iw = ii - ih * 7, jh = jj / 7, jw = jj - jh * 7;
            v = rpb[((ih - jh + 6) * 13 + (iw - jw + 6)) * 4 + h];
            int WH = (wt & 2) ? 49 : 0, WW = (wt & 1) ? 49 : 0;
            if (region(WH + ih, WW + iw) != region(WH + jh, WW + jw)) v -= 100.f;
        }
        bm[idx] = v;
    }
}

// ---- kernel A: LN1 + SW-MSA + proj + residual ----
// one block per (batch, window); LDS 40448 -> 4 blocks/CU
__global__ __launch_bounds__(256, 4) void swin_kernel(
    const float* __restrict__ x,
    const float* __restrict__ g1, const float* __restrict__ b1,
    const float* __restrict__ qkv_b, const float* __restrict__ proj_b,
    const __bf16* __restrict__ wqkv, const __bf16* __restrict__ wproj,
    const float* __restrict__ bm,
    float* __restrict__ out)
{
    __shared__ __bf16 a_s[64 * 136];               // LN1 out
    __shared__ __align__(16) char u_s[23040];      // phase union
    __bf16* QKs = (__bf16*)u_s;                    // 64 x 72 (Q | K)
    __bf16* VTs = (__bf16*)(u_s + 9216);           // 32 x 72 (V^T)
    __bf16* PSs = (__bf16*)(u_s + 13824);          // 64 x 72 (softmax P)
    __bf16* OSs = (__bf16*)u_s;                    // 64 x 136 (attn O)

    const int tid = threadIdx.x, w = tid >> 6, lane = tid & 63;
    const int quad = lane >> 4, r16 = lane & 15;
    const int blk = blockIdx.x, b = blk >> 6, wi = blk & 63;
    const int wh = wi >> 3, ww = wi & 7;
    const int wt = ((wh == 7) ? 2 : 0) | ((ww == 7) ? 1 : 0);
    const float scale = 0.17677669529663687f;  // 1/sqrt(32)

    // ---- LN1 with shifted gather (2 tokens/iter, 4 interleaved shfl chains) ----
    for (int t = w; t < 49; t += 8) {
        int t2 = t + 4; bool has2 = (t2 < 49);
        int th = t / 7, tw = t - th * 7;
        int sh = wh * 7 + th + 3; if (sh >= 56) sh -= 56;
        int sw = ww * 7 + tw + 3; if (sw >= 56) sw -= 56;
        int rowA = (b * L_ + sh * 56 + sw) * Cc;
        int rowB = rowA;
        if (has2) {
            int th2 = t2 / 7, tw2 = t2 - th2 * 7;
            int sh2 = wh * 7 + th2 + 3; if (sh2 >= 56) sh2 -= 56;
            int sw2 = ww * 7 + tw2 + 3; if (sw2 >= 56) sw2 -= 56;
            rowB = (b * L_ + sh2 * 56 + sw2) * Cc;
        }
        float a0 = x[rowA + lane], a1 = x[rowA + 64 + lane];
        float c0 = x[rowB + lane], c1 = x[rowB + 64 + lane];
        float sA = a0 + a1, qA = a0 * a0 + a1 * a1;
        float sB = c0 + c1, qB = c0 * c0 + c1 * c1;
        for (int off = 32; off; off >>= 1) {
            sA += __shfl_down(sA, off, 64); qA += __shfl_down(qA, off, 64);
            sB += __shfl_down(sB, off, 64); qB += __shfl_down(qB, off, 64);
        }
        sA = __shfl(sA, 0, 64); qA = __shfl(qA, 0, 64);
        sB = __shfl(sB, 0, 64); qB = __shfl(qB, 0, 64);
        {
            float mu = sA * (1.f / 128.f);
            float rs = rsqrtf(qA * (1.f / 128.f) - mu * mu + 1e-5f);
            a_s[t * 136 + lane]      = (__bf16)((a0 - mu) * rs * g1[lane]      + b1[lane]);
            a_s[t * 136 + 64 + lane] = (__bf16)((a1 - mu) * rs * g1[64 + lane] + b1[64 + lane]);
        }
        if (has2) {
            float mu = sB * (1.f / 128.f);
            float rs = rsqrtf(qB * (1.f / 128.f) - mu * mu + 1e-5f);
            a_s[t2 * 136 + lane]      = (__bf16)((c0 - mu) * rs * g1[lane]      + b1[lane]);
            a_s[t2 * 136 + 64 + lane] = (__bf16)((c1 - mu) * rs * g1[64 + lane] + b1[64 + lane]);
        }
    }
    for (int idx = tid; idx < 15 * 128; idx += 256) {
        int rr = idx >> 7, cc = idx & 127;
        a_s[(49 + rr) * 136 + cc] = (__bf16)0.f;
    }
    __syncthreads();

    // ---- attention: O accumulates in registers ----
    f4v o_acc[4][2];
    #pragma unroll
    for (int h = 0; h < 4; h++)
        #pragma unroll
        for (int n = 0; n < 2; n++)
            o_acc[h][n] = (f4v){0.f, 0.f, 0.f, 0.f};

    const float* bmw = bm + wt * 4 * 4096;

    for (int h = 0; h < 4; h++) {
        // QKV for this head: wave w owns M-strip mt=w; nt=0..5 (Q,Q,K,K,V,V)
        {
            const __bf16* ap = &a_s[(w * 16 + r16) * 136 + quad * 8];
            b8v A0 = *(const b8v*)(ap);
            b8v A1 = *(const b8v*)(ap + 32);
            b8v A2 = *(const b8v*)(ap + 64);
            b8v A3 = *(const b8v*)(ap + 96);
            #pragma unroll
            for (int nt = 0; nt < 6; nt++) {
                int base = (nt < 2) ? (h * 32 + nt * 16)
                         : (nt < 4) ? (128 + h * 32 + (nt - 2) * 16)
                                    : (256 + h * 32 + (nt - 4) * 16);
                const __bf16* bp = wqkv + (base + r16) * 128 + quad * 8;
                f4v acc = {0.f, 0.f, 0.f, 0.f};
                acc = mfma16(A0, *(const b8v*)(bp),      acc);
                acc = mfma16(A1, *(const b8v*)(bp + 32), acc);
                acc = mfma16(A2, *(const b8v*)(bp + 64), acc);
                acc = mfma16(A3, *(const b8v*)(bp + 96), acc);
                float bias = qkv_b[base + r16];
                #pragma unroll
                for (int r = 0; r < 4; r++) {
                    int m = w * 16 + quad * 4 + r;
                    float v = acc[r] + bias;
                    if (nt < 2)      QKs[m * 72 + nt * 16 + r16]            = (__bf16)(v * scale);
                    else if (nt < 4) QKs[m * 72 + 32 + (nt - 2) * 16 + r16] = (__bf16)v;
                    else             VTs[((nt - 4) * 16 + r16) * 72 + m]    = (__bf16)v;
                }
            }
        }
        __syncthreads();

        // S = Q K^T + (bias+mask table)
        f4v s[4];
        {
            b8v qf = *(const b8v*)&QKs[(w * 16 + r16) * 72 + quad * 8];
            #pragma unroll
            for (int nt = 0; nt < 4; nt++) {
                b8v kf = *(const b8v*)&QKs[(nt * 16 + r16) * 72 + 32 + quad * 8];
                f4v z = {0.f, 0.f, 0.f, 0.f};
                s[nt] = mfma16(qf, kf, z);
            }
            const float* bmp = bmw + h * 4096 + (w * 16 + quad * 4) * 64 + r16;
            #pragma unroll
            for (int nt = 0; nt < 4; nt++)
                #pragma unroll
                for (int r = 0; r < 4; r++)
                    s[nt][r] += bmp[r * 64 + nt * 16];
        }
        // softmax: 4 rows, shfl chains interleaved
        {
            float mx[4], sm[4];
            #pragma unroll
            for (int r = 0; r < 4; r++)
                mx[r] = fmaxf(fmaxf(s[0][r], s[1][r]), fmaxf(s[2][r], s[3][r]));
            #pragma unroll
            for (int mk = 1; mk < 16; mk <<= 1)
                #pragma unroll
                for (int r = 0; r < 4; r++)
                    mx[r] = fmaxf(mx[r], __shfl_xor(mx[r], mk, 64));
            #pragma unroll
            for (int r = 0; r < 4; r++) {
                s[0][r] = expf(s[0][r] - mx[r]);
                s[1][r] = expf(s[1][r] - mx[r]);
                s[2][r] = expf(s[2][r] - mx[r]);
                s[3][r] = expf(s[3][r] - mx[r]);
                sm[r] = s[0][r] + s[1][r] + s[2][r] + s[3][r];
            }
            #pragma unroll
            for (int mk = 1; mk < 16; mk <<= 1)
                #pragma unroll
                for (int r = 0; r < 4; r++)
                    sm[r] += __shfl_xor(sm[r], mk, 64);
            #pragma unroll
            for (int r = 0; r < 4; r++) {
                float inv = 1.f / sm[r];
                s[0][r] *= inv; s[1][r] *= inv; s[2][r] *= inv; s[3][r] *= inv;
            }
        }
        // P -> LDS (D->A transform, wave-local strip)
        #pragma unroll
        for (int nt = 0; nt < 4; nt++)
            #pragma unroll
            for (int r = 0; r < 4; r++)
                PSs[(w * 16 + quad * 4 + r) * 72 + nt * 16 + r16] = (__bf16)s[nt][r];

        // O += P V (register accumulation)
        #pragma unroll
        for (int nt = 0; nt < 2; nt++)
            #pragma unroll
            for (int ks = 0; ks < 2; ks++) {
                b8v pf = *(const b8v*)&PSs[(w * 16 + r16) * 72 + ks * 32 + quad * 8];
                b8v vf = *(const b8v*)&VTs[(nt * 16 + r16) * 72 + ks * 32 + quad * 8];
                o_acc[h][nt] = mfma16(pf, vf, o_acc[h][nt]);
            }
        __syncthreads();
    }

    // O regs -> LDS (union now free)
    #pragma unroll
    for (int h = 0; h < 4; h++)
        #pragma unroll
        for (int nt = 0; nt < 2; nt++)
            #pragma unroll
            for (int r = 0; r < 4; r++)
                OSs[(w * 16 + quad * 4 + r) * 136 + h * 32 + nt * 16 + r16] = (__bf16)o_acc[h][nt][r];
    __syncthreads();

    // ---- proj + residual: write x1 to out (fp32); LN2/MLP in kernel B ----
    {
        const __bf16* ap = &OSs[(w * 16 + r16) * 136 + quad * 8];
        b8v A0 = *(const b8v*)(ap);
        b8v A1 = *(const b8v*)(ap + 32);
        b8v A2 = *(const b8v*)(ap + 64);
        b8v A3 = *(const b8v*)(ap + 96);
        #pragma unroll
        for (int nt = 0; nt < 8; nt++) {
            const __bf16* bp = wproj + (nt * 16 + r16) * 128 + quad * 8;
            f4v acc = {0.f, 0.f, 0.f, 0.f};
            acc = mfma16(A0, *(const b8v*)(bp),      acc);
            acc = mfma16(A1, *(const b8v*)(bp + 32), acc);
            acc = mfma16(A2, *(const b8v*)(bp + 64), acc);
            acc = mfma16(A3, *(const b8v*)(bp + 96), acc);
            int col = nt * 16 + r16;
            float pb = proj_b[col];
            #pragma unroll
            for (int r = 0; r < 4; r++) {
                int t = w * 16 + quad * 4 + r;
                if (t < 49) {
                    int th = t / 7, tw = t - th * 7;
                    int sh = wh * 7 + th + 3; if (sh >= 56) sh -= 56;
                    int sw = ww * 7 + tw + 3; if (sw >= 56) sw -= 56;
                    int off = (b * L_ + sh * 56 + sw) * Cc + col;
                    out[off] = x[off] + acc[r] + pb;
                }
            }
        }
    }
}

// ---- kernel B v2: LN2 + fc1 + GELU + fc2 + residual ----
// block = 32 contiguous tokens, 4 waves. Weights column-sliced per wave:
// each weight element loaded ONCE per block (was once per wave). LDS union
// 33280 B -> 4 blocks/CU (16 waves). Vectorized f4v residual epilogue.
__global__ __launch_bounds__(256, 4) void mlp_kernel(
    float* __restrict__ out,
    const float* __restrict__ g2, const float* __restrict__ b2,
    const __bf16* __restrict__ wfc1, const __bf16* __restrict__ wfc2,
    const float* __restrict__ fc1_b, const float* __restrict__ fc2_b)
{
    __shared__ __align__(16) char u_s[33280];
    __bf16* x2  = (__bf16*)u_s;     // [32][136] LN2 output
    __bf16* h1  = (__bf16*)u_s;     // [32][520] GELU(fc1) output
    float*  o_s = (float*)u_s;      // [32][130] fc2 output (pre-residual)

    const int tid = threadIdx.x, w = tid >> 6, lane = tid & 63;
    const int quad = lane >> 4, r16 = lane & 15;
    const int rowbase = blockIdx.x * 32;

    // ---- LN2: wave w -> rows w*8..w*8+7; lane: r=lane>>3, cols (lane&7)*16..+15 ----
    {
        const int r = lane >> 3, sub = lane & 7;
        const float* xp = out + (rowbase + w * 8 + r) * Cc + sub * 16;
        f4v xa[4];
        #pragma unroll
        for (int j = 0; j < 4; j++) xa[j] = *(const f4v*)(xp + j * 4);
        float s = 0.f, q = 0.f;
        #pragma unroll
        for (int j = 0; j < 4; j++)
            #pragma unroll
            for (int e = 0; e < 4; e++) { float v = xa[j][e]; s += v; q += v * v; }
        s += __shfl_xor(s, 1, 64); q += __shfl_xor(q, 1, 64);
        s += __shfl_xor(s, 2, 64); q += __shfl_xor(q, 2, 64);
        s += __shfl_xor(s, 4, 64); q += __shfl_xor(q, 4, 64);
        float mu = s * (1.f / 128.f);
        float rs = rsqrtf(q * (1.f / 128.f) - mu * mu + 1e-5f);
        #pragma unroll
        for (int half = 0; half < 2; half++) {
            int c = sub * 16 + half * 8;
            f4v gg0 = *(const f4v*)(g2 + c), gg1 = *(const f4v*)(g2 + c + 4);
            f4v bb0 = *(const f4v*)(b2 + c), bb1 = *(const f4v*)(b2 + c + 4);
            b8v o;
            #pragma unroll
            for (int e = 0; e < 4; e++) {
                o[e]     = (__bf16)((xa[half * 2][e]     - mu) * rs * gg0[e] + bb0[e]);
                o[4 + e] = (__bf16)((xa[half * 2 + 1][e] - mu) * rs * gg1[e] + bb1[e]);
            }
            *(b8v*)(x2 + (w * 8 + r) * 136 + c) = o;
        }
    }
    __syncthreads();

    // ---- A-fragments for ALL 32 rows into registers (8 b8v) ----
    b8v af[2][4];
    #pragma unroll
    for (int mt = 0; mt < 2; mt++)
        #pragma unroll
        for (int i = 0; i < 4; i++)
            af[mt][i] = *(const b8v*)&x2[(mt * 16 + r16) * 136 + quad * 8 + i * 32];
    __syncthreads();  // x2 region free; h1 writes may begin

    // ---- fc1 + exact GELU: wave w owns nt = w*8..w*8+7 (hidden cols) ----
    #pragma unroll 2
    for (int k8 = 0; k8 < 8; k8++) {
        const int nt = w * 8 + k8;
        const __bf16* bp = wfc1 + (nt * 16 + r16) * 128 + quad * 8;
        b8v Bf0 = *(const b8v*)(bp),      Bf1 = *(const b8v*)(bp + 32);
        b8v Bf2 = *(const b8v*)(bp + 64), Bf3 = *(const b8v*)(bp + 96);
        f4v acc0 = {0.f, 0.f, 0.f, 0.f}, acc1 = {0.f, 0.f, 0.f, 0.f};
        acc0 = mfma16(af[0][0], Bf0, acc0); acc1 = mfma16(af[1][0], Bf0, acc1);
        acc0 = mfma16(af[0][1], Bf1, acc0); acc1 = mfma16(af[1][1], Bf1, acc1);
        acc0 = mfma16(af[0][2], Bf2, acc0); acc1 = mfma16(af[1][2], Bf2, acc1);
        acc0 = mfma16(af[0][3], Bf3, acc0); acc1 = mfma16(af[1][3], Bf3, acc1);
        float bias = fc1_b[nt * 16 + r16];
        #pragma unroll
        for (int mt = 0; mt < 2; mt++) {
            #pragma unroll
            for (int rr = 0; rr < 4; rr++) {
                float v = (mt ? acc1[rr] : acc0[rr]) + bias;
                v = 0.5f * v * (1.f + erff(v * 0.70710678118654752f));
                h1[(mt * 16 + quad * 4 + rr) * 520 + nt * 16 + r16] = (__bf16)v;
            }
        }
    }
    __syncthreads();

    // ---- fc2: wave w owns out-cols (w*2..w*2+1)*16; A from shared h1 ----
    f4v acc[2][2];  // [j: out-tile][mt: row-tile]
    acc[0][0] = (f4v){0.f,0.f,0.f,0.f}; acc[0][1] = (f4v){0.f,0.f,0.f,0.f};
    acc[1][0] = (f4v){0.f,0.f,0.f,0.f}; acc[1][1] = (f4v){0.f,0.f,0.f,0.f};
    {
        const __bf16* bp0 = wfc2 + ((w * 2) * 16 + r16) * 512 + quad * 8;
        const __bf16* bp1 = bp0 + 16 * 512;
        #pragma unroll 4
        for (int ks = 0; ks < 16; ks++) {
            b8v a0 = *(const b8v*)&h1[r16 * 520 + ks * 32 + quad * 8];
            b8v a1 = *(const b8v*)&h1[(16 + r16) * 520 + ks * 32 + quad * 8];
            b8v B0 = *(const b8v*)(bp0 + ks * 32);
            b8v B1 = *(const b8v*)(bp1 + ks * 32);
            acc[0][0] = mfma16(a0, B0, acc[0][0]);
            acc[0][1] = mfma16(a1, B0, acc[0][1]);
            acc[1][0] = mfma16(a0, B1, acc[1][0]);
            acc[1][1] = mfma16(a1, B1, acc[1][1]);
        }
    }
    __syncthreads();  // all h1 reads complete before o_s overwrites the union

    // ---- fc2 D-frags + bias -> o_s ----
    #pragma unroll
    for (int j = 0; j < 2; j++) {
        int colb = (w * 2 + j) * 16 + r16;
        float fb = fc2_b[colb];
        #pragma unroll
        for (int mt = 0; mt < 2; mt++)
            #pragma unroll
            for (int rr = 0; rr < 4; rr++)
                o_s[(mt * 16 + quad * 4 + rr) * 130 + colb] = acc[j][mt][rr] + fb;
    }
    __syncthreads();

    // ---- vectorized residual RMW: thread -> 16 contiguous floats of out ----
    {
        const int row = tid >> 3, colb = (tid & 7) * 16;
        float* op = out + (rowbase + row) * Cc + colb;
        const float* ls = o_s + row * 130 + colb;
        #pragma unroll
        for (int j = 0; j < 4; j++) {
            f4v v = *(const f4v*)(op + j * 4);
            v += *(const f4v*)(ls + j * 4);
            *(f4v*)(op + j * 4) = v;
        }
    }
}

extern "C" void kernel_launch(void* const* d_in, const int* in_sizes, int n_in,
                              void* d_out, int out_size, void* d_ws, size_t ws_size,
                              hipStream_t stream) {
    // 0 x, 1 ln1_g, 2 ln1_b, 3 qkv_w, 4 qkv_b, 5 rpb_table, 6 proj_w, 7 proj_b,
    // 8 ln2_g, 9 ln2_b, 10 fc1_w, 11 fc1_b, 12 fc2_w, 13 fc2_b
    __bf16* wsb = (__bf16*)d_ws;
    float*  bmp = (float*)((char*)d_ws + 393216);
    prep_kernel<<<1024, 256, 0, stream>>>(
        (const float*)d_in[3], (const float*)d_in[6],
        (const float*)d_in[10], (const float*)d_in[12],
        (const float*)d_in[5], wsb, bmp);
    swin_kernel<<<B_ * 64, 256, 0, stream>>>(
        (const float*)d_in[0],
        (const float*)d_in[1], (const float*)d_in[2],
        (const float*)d_in[4], (const float*)d_in[7],
        wsb, wsb + 49152,
        bmp, (float*)d_out);
    mlp_kernel<<<B_ * 98, 256, 0, stream>>>(
        (float*)d_out,
        (const float*)d_in[8], (const float*)d_in[9],
        wsb + 65536, wsb + 131072,
        (const float*)d_in[11], (const float*)d_in[13]);
}